// Round 5
// baseline (1592.487 us; speedup 1.0000x reference)
//
#include <hip/hip_runtime.h>

// TwoDimensionalSSM via direct 2D recurrence. Round 5: kill the spill.
// Evidence: R2/R3/R4 all had VGPR_Count=64 + GBs of scratch traffic with
// __launch_bounds__(256,4); R1 (no 2nd arg) had VGPR=88 and zero spill.
// Theory: the min-waves arg makes the allocator target 8 waves/EU (64-VGPR
// budget) and spill ~90 live values. Fix: (a) plain __launch_bounds__(256),
// (b) accumulator as 32 NAMED scalars via macros (mem2reg-guaranteed), four
// macro-unrolled single-direction sweeps, SiLU fused into the last sweep.

#define NPB 8            // images per block (one per 32-lane half, 2/wave)
#define THREADS 256
#define M_TOT 16384      // B*E
#define SCALE 0.70710678118654752f  // sqrt(1/N), N=2

#define FOR32(M) M(0) M(1) M(2) M(3) M(4) M(5) M(6) M(7) \
                 M(8) M(9) M(10) M(11) M(12) M(13) M(14) M(15) \
                 M(16) M(17) M(18) M(19) M(20) M(21) M(22) M(23) \
                 M(24) M(25) M(26) M(27) M(28) M(29) M(30) M(31)
#define FOR32R(M) M(31) M(30) M(29) M(28) M(27) M(26) M(25) M(24) \
                  M(23) M(22) M(21) M(20) M(19) M(18) M(17) M(16) \
                  M(15) M(14) M(13) M(12) M(11) M(10) M(9) M(8) \
                  M(7) M(6) M(5) M(4) M(3) M(2) M(1) M(0)

template<int CTRL, int ROW_MASK, bool BC>
__device__ __forceinline__ float dppf(float v) {
    return __int_as_float(__builtin_amdgcn_update_dpp(
        0, __float_as_int(v), CTRL, ROW_MASK, 0xF, BC));
}

__device__ __forceinline__ float sigm(float v) { return 1.0f / (1.0f + __expf(-v)); }

// forward inclusive scan over each 32-lane half: out[j] = sum_{q<=j} a^(j-q) in[q]
__device__ __forceinline__ float scanF(float v, float a, float p2, float p4,
                                       float p8, float w) {
    v = fmaf(a,  dppf<0x111, 0xF, true >(v), v);  // row_shr:1
    v = fmaf(p2, dppf<0x112, 0xF, true >(v), v);  // row_shr:2
    v = fmaf(p4, dppf<0x114, 0xF, true >(v), v);  // row_shr:4
    v = fmaf(p8, dppf<0x118, 0xF, true >(v), v);  // row_shr:8
    v = fmaf(w,  dppf<0x142, 0xA, false>(v), v);  // row_bcast15 -> rows 1,3
    return v;
}

// reverse inclusive scan over each 32-lane half: out[j] = sum_{q>=j} a^(q-j) in[q]
__device__ __forceinline__ float scanR(float v, float a, float p2, float p4,
                                       float p8, float w) {
    v = fmaf(a,  dppf<0x101, 0xF, true>(v), v);   // row_shl:1
    v = fmaf(p2, dppf<0x102, 0xF, true>(v), v);   // row_shl:2
    v = fmaf(p4, dppf<0x104, 0xF, true>(v), v);   // row_shl:4
    v = fmaf(p8, dppf<0x108, 0xF, true>(v), v);   // row_shl:8
    // bit-mode ds_swizzle 0x0200: src = lane16 of each 32-half
    float b = __int_as_float(__builtin_amdgcn_ds_swizzle(__float_as_int(v), 0x0200));
    v = fmaf(w, b, v);
    return v;
}

struct DirP {
    float a1_0, a1_1, p2_0, p2_1, p4_0, p4_1, p8_0, p8_1, w_0, w_1;
    float a2z0, a2z1, ab0, ab1, a3_0, a3_1, a4_0, a4_1;
    float b1_0, b1_1, b2_0, b2_1, a3b1_0, a3b1_1;
    float c1s0, c1s1, c2s0, c2s1, k00;
};

template<bool REV>
__device__ __forceinline__ void dir_init(DirP& P, int h, int j,
    const float* __restrict__ A1p, const float* __restrict__ A2p,
    const float* __restrict__ A3p, const float* __restrict__ A4p,
    const float* __restrict__ B1p, const float* __restrict__ B2p,
    const float* __restrict__ C1p, const float* __restrict__ C2p)
{
    float2 a1r = *(const float2*)(A1p + 2 * h);
    float2 a2r = *(const float2*)(A2p + 2 * h);
    float2 a3r = *(const float2*)(A3p + 2 * h);
    float2 a4r = *(const float2*)(A4p + 2 * h);
    float2 b1r = *(const float2*)(B1p + 2 * h);
    float2 b2r = *(const float2*)(B2p + 2 * h);
    float2 c1r = *(const float2*)(C1p + 2 * h);
    float2 c2r = *(const float2*)(C2p + 2 * h);
    P.a1_0 = sigm(a1r.x); P.a1_1 = sigm(a1r.y);
    float a2n0 = sigm(a2r.x), a2n1 = sigm(a2r.y);
    P.a3_0 = sigm(a3r.x); P.a3_1 = sigm(a3r.y);
    P.a4_0 = sigm(a4r.x); P.a4_1 = sigm(a4r.y);
    P.b1_0 = sigm(b1r.x); P.b1_1 = sigm(b1r.y);
    P.b2_0 = sigm(b2r.x); P.b2_1 = sigm(b2r.y);
    P.c1s0 = SCALE * c1r.x; P.c1s1 = SCALE * c1r.y;
    P.c2s0 = SCALE * c2r.x; P.c2s1 = SCALE * c2r.y;
    P.k00  = P.c1s0 * P.b1_0 + P.c1s1 * P.b1_1 + P.c2s0 * P.b2_0 + P.c2s1 * P.b2_1;
    // boundary kill: fwd at j==0 (also kills wave_shr cross-half leak),
    // rev at j==31 (kills wave_shl cross-half leak)
    const bool edge = REV ? (j == 31) : (j == 0);
    P.a2z0 = edge ? 0.f : a2n0;
    P.a2z1 = edge ? 0.f : a2n1;
    P.ab0  = P.a2z0 * P.b2_0; P.ab1 = P.a2z1 * P.b2_1;
    P.a3b1_0 = P.a3_0 * P.b1_0; P.a3b1_1 = P.a3_1 * P.b1_1;
    P.p2_0 = P.a1_0 * P.a1_0; P.p4_0 = P.p2_0 * P.p2_0; P.p8_0 = P.p4_0 * P.p4_0;
    P.p2_1 = P.a1_1 * P.a1_1; P.p4_1 = P.p2_1 * P.p2_1; P.p8_1 = P.p4_1 * P.p4_1;
    if (REV) {
        P.w_0 = ((j & 16) == 0) ? __powf(P.a1_0, (float)(16 - (j & 15))) : 0.f;
        P.w_1 = ((j & 16) == 0) ? __powf(P.a1_1, (float)(16 - (j & 15))) : 0.f;
    } else {
        P.w_0 = __powf(P.a1_0, (float)((j & 15) + 1));
        P.w_1 = __powf(P.a1_1, (float)((j & 15) + 1));
    }
}

template<bool REV>
__device__ __forceinline__ float dir_step(const DirP& P, float u,
    float& xh0, float& xh1, float& xv0, float& xv1,
    float& cx0, float& cx1, float& up)
{
    float b2u0 = P.b2_0 * u, b2u1 = P.b2_1 * u;
    float nxv0 = fmaf(P.a3_0, xh0, fmaf(P.a4_0, xv0, b2u0));
    float nxv1 = fmaf(P.a3_1, xh1, fmaf(P.a4_1, xv1, b2u1));
    float ncx0 = fmaf(P.a3b1_0, up, fmaf(P.a4_0, cx0, b2u0));
    float ncx1 = fmaf(P.a3b1_1, up, fmaf(P.a4_1, cx1, b2u1));
    float xl0, xl1, ul;
    if (REV) {   // neighbor = column j+1 -> wave_shl:1
        xl0 = dppf<0x130, 0xF, true>(nxv0);
        xl1 = dppf<0x130, 0xF, true>(nxv1);
        ul  = dppf<0x130, 0xF, true>(u);
    } else {     // neighbor = column j-1 -> wave_shr:1
        xl0 = dppf<0x138, 0xF, true>(nxv0);
        xl1 = dppf<0x138, 0xF, true>(nxv1);
        ul  = dppf<0x138, 0xF, true>(u);
    }
    float b1u0 = P.b1_0 * u, b1u1 = P.b1_1 * u;
    float d0 = fmaf(P.a2z0, xl0, b1u0);
    float d1 = fmaf(P.a2z1, xl1, b1u1);
    float e0 = fmaf(P.ab0, ul, b1u0);
    float e1 = fmaf(P.ab1, ul, b1u1);
    float nh0, nh1, rh0, rh1;
    if (REV) {
        nh0 = scanR(d0, P.a1_0, P.p2_0, P.p4_0, P.p8_0, P.w_0);
        nh1 = scanR(d1, P.a1_1, P.p2_1, P.p4_1, P.p8_1, P.w_1);
        rh0 = scanR(e0, P.a1_0, P.p2_0, P.p4_0, P.p8_0, P.w_0);
        rh1 = scanR(e1, P.a1_1, P.p2_1, P.p4_1, P.p8_1, P.w_1);
    } else {
        nh0 = scanF(d0, P.a1_0, P.p2_0, P.p4_0, P.p8_0, P.w_0);
        nh1 = scanF(d1, P.a1_1, P.p2_1, P.p4_1, P.p8_1, P.w_1);
        rh0 = scanF(e0, P.a1_0, P.p2_0, P.p4_0, P.p8_0, P.w_0);
        rh1 = scanF(e1, P.a1_1, P.p2_1, P.p4_1, P.p8_1, P.w_1);
    }
    float y = fmaf(P.c1s0, nh0 + rh0, fmaf(P.c1s1, nh1 + rh1,
              fmaf(P.c2s0, nxv0 + ncx0, fmaf(P.c2s1, nxv1 + ncx1, -P.k00 * u))));
    xh0 = nh0; xh1 = nh1; xv0 = nxv0; xv1 = nxv1;
    cx0 = ncx0; cx1 = ncx1; up = u;
    return y;
}

__global__ __launch_bounds__(THREADS) void ssm2d_kernel(
    const float* __restrict__ x,
    const float* __restrict__ A1p, const float* __restrict__ A2p,
    const float* __restrict__ A3p, const float* __restrict__ A4p,
    const float* __restrict__ B1p, const float* __restrict__ B2p,
    const float* __restrict__ C1p, const float* __restrict__ C2p,
    const float* __restrict__ omega,
    float* __restrict__ out)
{
    __shared__ float u_lds[NPB * 1024];   // 32 KB; XOR-swizzled addressing
    const int t = threadIdx.x;
    // XCD-aware remap: blocks on the same XCD (bid%8 fixed) cover adjacent
    // m-ranges so both halves of each 64B x-line hit the same L2.
    const int bid = blockIdx.x;
    const int m0  = ((bid & 7) * 256 + (bid >> 3)) * NPB;

    // ---- stage x into LDS; XOR swizzle (pix ^ 4*img) kills 8-way conflicts ----
    const int simg = t & 7;
    #pragma unroll 4
    for (int it = 0; it < 32; ++it) {
        int pix = it * 32 + (t >> 3);
        u_lds[simg * 1024 + (pix ^ (simg << 2))] = x[(size_t)pix * M_TOT + (m0 + simg)];
    }
    __syncthreads();

    const int j   = t & 31;
    const int img = t >> 5;
    const int m   = m0 + img;
    const int colx = j ^ (img << 2);      // per-lane LDS column (bank-distinct)
    float* uim = u_lds + img * 1024;
    const float om = omega[m & 1023];
    const int hb = m & 63;

    // 32 NAMED scalar accumulators -> mem2reg promotes unconditionally.
    #define DECL_ACC(i) float acc##i;
    FOR32(DECL_ACC)
    #undef DECL_ACC

    {   // d0: rows ascending, forward scan (init acc + residual)
        DirP P; dir_init<false>(P, hb, j, A1p, A2p, A3p, A4p, B1p, B2p, C1p, C2p);
        float xh0=0,xh1=0,xv0=0,xv1=0,cx0=0,cx1=0,up=0;
        #define STEP(i) { float u = uim[(i) * 32 + colx]; \
            float y = dir_step<false>(P, u, xh0,xh1,xv0,xv1,cx0,cx1,up); \
            acc##i = fmaf(u, om, y); }
        FOR32(STEP)
        #undef STEP
    }
    {   // d2: rows ascending, reverse scan
        DirP P; dir_init<true>(P, 128 + hb, j, A1p, A2p, A3p, A4p, B1p, B2p, C1p, C2p);
        float xh0=0,xh1=0,xv0=0,xv1=0,cx0=0,cx1=0,up=0;
        #define STEP(i) { float u = uim[(i) * 32 + colx]; \
            float y = dir_step<true>(P, u, xh0,xh1,xv0,xv1,cx0,cx1,up); \
            acc##i += y; }
        FOR32(STEP)
        #undef STEP
    }
    {   // d1: rows descending, forward scan
        DirP P; dir_init<false>(P, 64 + hb, j, A1p, A2p, A3p, A4p, B1p, B2p, C1p, C2p);
        float xh0=0,xh1=0,xv0=0,xv1=0,cx0=0,cx1=0,up=0;
        #define STEP(i) { float u = uim[(i) * 32 + colx]; \
            float y = dir_step<false>(P, u, xh0,xh1,xv0,xv1,cx0,cx1,up); \
            acc##i += y; }
        FOR32R(STEP)
        #undef STEP
    }
    {   // d3: rows descending, reverse scan + fused SiLU + in-place writeback
        DirP P; dir_init<true>(P, 192 + hb, j, A1p, A2p, A3p, A4p, B1p, B2p, C1p, C2p);
        float xh0=0,xh1=0,xv0=0,xv1=0,cx0=0,cx1=0,up=0;
        #define STEP(i) { float u = uim[(i) * 32 + colx]; \
            float y = dir_step<true>(P, u, xh0,xh1,xv0,xv1,cx0,cx1,up); \
            float z = acc##i + y; \
            float sg = 1.0f / (1.0f + __expf(-z)); \
            uim[(i) * 32 + colx] = z * sg; }
        FOR32R(STEP)
        #undef STEP
    }
    __syncthreads();

    // ---- coalesced store-out ----
    #pragma unroll 4
    for (int it = 0; it < 32; ++it) {
        int pix = it * 32 + (t >> 3);
        out[(size_t)pix * M_TOT + (m0 + simg)] =
            u_lds[simg * 1024 + (pix ^ (simg << 2))];
    }
}

extern "C" void kernel_launch(void* const* d_in, const int* in_sizes, int n_in,
                              void* d_out, int out_size, void* d_ws, size_t ws_size,
                              hipStream_t stream) {
    const float* x  = (const float*)d_in[0];
    const float* A1 = (const float*)d_in[1];
    const float* A2 = (const float*)d_in[2];
    const float* A3 = (const float*)d_in[3];
    const float* A4 = (const float*)d_in[4];
    const float* B1 = (const float*)d_in[5];
    const float* B2 = (const float*)d_in[6];
    const float* C1 = (const float*)d_in[7];
    const float* C2 = (const float*)d_in[8];
    const float* om = (const float*)d_in[9];
    float* out = (float*)d_out;
    hipLaunchKernelGGL(ssm2d_kernel, dim3(M_TOT / NPB), dim3(THREADS), 0, stream,
                       x, A1, A2, A3, A4, B1, B2, C1, C2, om, out);
}

// Round 6
// 258.923 us; speedup vs baseline: 6.1504x; 6.1504x over previous
//
#include <hip/hip_runtime.h>
#include <hip/hip_fp16.h>

// TwoDimensionalSSM via direct 2D recurrence. Round 6: back to R1's proven
// LOOPED structure (the only non-spilling variant: VGPR 88, 204 us). R5
// post-mortem: fully-unrolled 6400-inst bodies blow up pre-RA scheduling ->
// spill regardless of how acc is expressed. Changes vs R1:
//   - two passes, two directions each (A: d0+d2 ascending, B: d1+d3
//     descending): per-row partial is consumed immediately -> no acc array
//     in registers, acc LDS ops 11/row -> 5/row.
//   - acc stored fp16 in LDS (16 KB): total LDS 64->48 KB -> 3 blocks/CU.
//   - plain __launch_bounds__(256) (the (256,4) clamp caused the R2-R4
//     64-VGPR spill disaster).
//   - SiLU fused into pass B, result written in-place to acc slot.

#define NPB 8            // images per block (one per 32-lane half, 2/wave)
#define THREADS 256
#define M_TOT 16384      // B*E
#define SCALE 0.70710678118654752f  // sqrt(1/N), N=2

template<int CTRL, int ROW_MASK, bool BC>
__device__ __forceinline__ float dppf(float v) {
    return __int_as_float(__builtin_amdgcn_update_dpp(
        0, __float_as_int(v), CTRL, ROW_MASK, 0xF, BC));
}

__device__ __forceinline__ float sigm(float v) { return 1.0f / (1.0f + __expf(-v)); }

// forward inclusive scan over each 32-lane half: out[j] = sum_{q<=j} a^(j-q) in[q]
__device__ __forceinline__ float scanF(float v, float a, float p2, float p4,
                                       float p8, float w) {
    v = fmaf(a,  dppf<0x111, 0xF, true >(v), v);  // row_shr:1
    v = fmaf(p2, dppf<0x112, 0xF, true >(v), v);  // row_shr:2
    v = fmaf(p4, dppf<0x114, 0xF, true >(v), v);  // row_shr:4
    v = fmaf(p8, dppf<0x118, 0xF, true >(v), v);  // row_shr:8
    v = fmaf(w,  dppf<0x142, 0xA, false>(v), v);  // row_bcast15 -> rows 1,3
    return v;
}

// reverse inclusive scan over each 32-lane half: out[j] = sum_{q>=j} a^(q-j) in[q]
__device__ __forceinline__ float scanR(float v, float a, float p2, float p4,
                                       float p8, float w) {
    v = fmaf(a,  dppf<0x101, 0xF, true>(v), v);   // row_shl:1
    v = fmaf(p2, dppf<0x102, 0xF, true>(v), v);   // row_shl:2
    v = fmaf(p4, dppf<0x104, 0xF, true>(v), v);   // row_shl:4
    v = fmaf(p8, dppf<0x108, 0xF, true>(v), v);   // row_shl:8
    // bit-mode ds_swizzle 0x0200: src = lane16 of each 32-half
    float b = __int_as_float(__builtin_amdgcn_ds_swizzle(__float_as_int(v), 0x0200));
    v = fmaf(w, b, v);
    return v;
}

struct DirP {
    float a1_0, a1_1, p2_0, p2_1, p4_0, p4_1, p8_0, p8_1, w_0, w_1;
    float a2z0, a2z1, ab0, ab1, a3_0, a3_1, a4_0, a4_1;
    float b1_0, b1_1, b2_0, b2_1, a3b1_0, a3b1_1;
    float c1s0, c1s1, c2s0, c2s1, k00;
};

template<bool REV>
__device__ __forceinline__ void dir_init(DirP& P, int h, int j,
    const float* __restrict__ A1p, const float* __restrict__ A2p,
    const float* __restrict__ A3p, const float* __restrict__ A4p,
    const float* __restrict__ B1p, const float* __restrict__ B2p,
    const float* __restrict__ C1p, const float* __restrict__ C2p)
{
    float2 a1r = *(const float2*)(A1p + 2 * h);
    float2 a2r = *(const float2*)(A2p + 2 * h);
    float2 a3r = *(const float2*)(A3p + 2 * h);
    float2 a4r = *(const float2*)(A4p + 2 * h);
    float2 b1r = *(const float2*)(B1p + 2 * h);
    float2 b2r = *(const float2*)(B2p + 2 * h);
    float2 c1r = *(const float2*)(C1p + 2 * h);
    float2 c2r = *(const float2*)(C2p + 2 * h);
    P.a1_0 = sigm(a1r.x); P.a1_1 = sigm(a1r.y);
    float a2n0 = sigm(a2r.x), a2n1 = sigm(a2r.y);
    P.a3_0 = sigm(a3r.x); P.a3_1 = sigm(a3r.y);
    P.a4_0 = sigm(a4r.x); P.a4_1 = sigm(a4r.y);
    P.b1_0 = sigm(b1r.x); P.b1_1 = sigm(b1r.y);
    P.b2_0 = sigm(b2r.x); P.b2_1 = sigm(b2r.y);
    P.c1s0 = SCALE * c1r.x; P.c1s1 = SCALE * c1r.y;
    P.c2s0 = SCALE * c2r.x; P.c2s1 = SCALE * c2r.y;
    P.k00  = P.c1s0 * P.b1_0 + P.c1s1 * P.b1_1 + P.c2s0 * P.b2_0 + P.c2s1 * P.b2_1;
    // boundary kill: fwd at j==0 (also kills wave_shr cross-half leak),
    // rev at j==31 (kills wave_shl cross-half leak)
    const bool edge = REV ? (j == 31) : (j == 0);
    P.a2z0 = edge ? 0.f : a2n0;
    P.a2z1 = edge ? 0.f : a2n1;
    P.ab0  = P.a2z0 * P.b2_0; P.ab1 = P.a2z1 * P.b2_1;
    P.a3b1_0 = P.a3_0 * P.b1_0; P.a3b1_1 = P.a3_1 * P.b1_1;
    P.p2_0 = P.a1_0 * P.a1_0; P.p4_0 = P.p2_0 * P.p2_0; P.p8_0 = P.p4_0 * P.p4_0;
    P.p2_1 = P.a1_1 * P.a1_1; P.p4_1 = P.p2_1 * P.p2_1; P.p8_1 = P.p4_1 * P.p4_1;
    if (REV) {
        P.w_0 = ((j & 16) == 0) ? __powf(P.a1_0, (float)(16 - (j & 15))) : 0.f;
        P.w_1 = ((j & 16) == 0) ? __powf(P.a1_1, (float)(16 - (j & 15))) : 0.f;
    } else {
        P.w_0 = __powf(P.a1_0, (float)((j & 15) + 1));
        P.w_1 = __powf(P.a1_1, (float)((j & 15) + 1));
    }
}

// up passed by VALUE (same u sequence for both dirs in a pass; caller updates).
template<bool REV>
__device__ __forceinline__ float dir_step(const DirP& P, float u, float up,
    float& xh0, float& xh1, float& xv0, float& xv1, float& cx0, float& cx1)
{
    float b2u0 = P.b2_0 * u, b2u1 = P.b2_1 * u;
    float nxv0 = fmaf(P.a3_0, xh0, fmaf(P.a4_0, xv0, b2u0));
    float nxv1 = fmaf(P.a3_1, xh1, fmaf(P.a4_1, xv1, b2u1));
    float ncx0 = fmaf(P.a3b1_0, up, fmaf(P.a4_0, cx0, b2u0));
    float ncx1 = fmaf(P.a3b1_1, up, fmaf(P.a4_1, cx1, b2u1));
    float xl0, xl1, ul;
    if (REV) {   // neighbor = column j+1 -> wave_shl:1
        xl0 = dppf<0x130, 0xF, true>(nxv0);
        xl1 = dppf<0x130, 0xF, true>(nxv1);
        ul  = dppf<0x130, 0xF, true>(u);
    } else {     // neighbor = column j-1 -> wave_shr:1
        xl0 = dppf<0x138, 0xF, true>(nxv0);
        xl1 = dppf<0x138, 0xF, true>(nxv1);
        ul  = dppf<0x138, 0xF, true>(u);
    }
    float b1u0 = P.b1_0 * u, b1u1 = P.b1_1 * u;
    float d0 = fmaf(P.a2z0, xl0, b1u0);
    float d1 = fmaf(P.a2z1, xl1, b1u1);
    float e0 = fmaf(P.ab0, ul, b1u0);
    float e1 = fmaf(P.ab1, ul, b1u1);
    float nh0, nh1, rh0, rh1;
    if (REV) {
        nh0 = scanR(d0, P.a1_0, P.p2_0, P.p4_0, P.p8_0, P.w_0);
        nh1 = scanR(d1, P.a1_1, P.p2_1, P.p4_1, P.p8_1, P.w_1);
        rh0 = scanR(e0, P.a1_0, P.p2_0, P.p4_0, P.p8_0, P.w_0);
        rh1 = scanR(e1, P.a1_1, P.p2_1, P.p4_1, P.p8_1, P.w_1);
    } else {
        nh0 = scanF(d0, P.a1_0, P.p2_0, P.p4_0, P.p8_0, P.w_0);
        nh1 = scanF(d1, P.a1_1, P.p2_1, P.p4_1, P.p8_1, P.w_1);
        rh0 = scanF(e0, P.a1_0, P.p2_0, P.p4_0, P.p8_0, P.w_0);
        rh1 = scanF(e1, P.a1_1, P.p2_1, P.p4_1, P.p8_1, P.w_1);
    }
    float y = fmaf(P.c1s0, nh0 + rh0, fmaf(P.c1s1, nh1 + rh1,
              fmaf(P.c2s0, nxv0 + ncx0, fmaf(P.c2s1, nxv1 + ncx1, -P.k00 * u))));
    xh0 = nh0; xh1 = nh1; xv0 = nxv0; xv1 = nxv1; cx0 = ncx0; cx1 = ncx1;
    return y;
}

__global__ __launch_bounds__(THREADS) void ssm2d_kernel(
    const float* __restrict__ x,
    const float* __restrict__ A1p, const float* __restrict__ A2p,
    const float* __restrict__ A3p, const float* __restrict__ A4p,
    const float* __restrict__ B1p, const float* __restrict__ B2p,
    const float* __restrict__ C1p, const float* __restrict__ C2p,
    const float* __restrict__ omega,
    float* __restrict__ out)
{
    __shared__ float  u_lds[NPB * 1024];   // 32 KB, XOR-swizzled
    __shared__ __half a_lds[NPB * 1024];   // 16 KB fp16 accumulator
    const int t = threadIdx.x;
    // XCD-aware remap: blocks on the same XCD (bid%8 fixed) cover adjacent
    // m-ranges so both halves of each 64B x-line hit the same L2.
    const int bid = blockIdx.x;
    const int m0  = ((bid & 7) * 256 + (bid >> 3)) * NPB;

    // ---- stage x into LDS; XOR swizzle (pix ^ 4*img) kills 8-way conflicts ----
    const int simg = t & 7;
    #pragma unroll 4
    for (int it = 0; it < 32; ++it) {
        int pix = it * 32 + (t >> 3);
        u_lds[simg * 1024 + (pix ^ (simg << 2))] = x[(size_t)pix * M_TOT + (m0 + simg)];
    }
    __syncthreads();

    const int j    = t & 31;
    const int img  = t >> 5;
    const int m    = m0 + img;
    const int colx = j ^ (img << 2);      // per-lane swizzled column
    const float*  uim = u_lds + img * 1024;
    __half*       aim = a_lds + img * 1024;
    const float om = omega[m & 1023];
    const int hb = m & 63;

    // ============ pass A: rows ascending, d0 (fwd) + d2 (rev) ============
    {
        DirP P0, P2;
        dir_init<false>(P0, hb,       j, A1p, A2p, A3p, A4p, B1p, B2p, C1p, C2p);
        dir_init<true >(P2, 128 + hb, j, A1p, A2p, A3p, A4p, B1p, B2p, C1p, C2p);
        float xh0a=0,xh1a=0,xv0a=0,xv1a=0,cx0a=0,cx1a=0;
        float xh0b=0,xh1b=0,xv0b=0,xv1b=0,cx0b=0,cx1b=0;
        float up = 0.f;
        #pragma unroll 4
        for (int s = 0; s < 32; ++s) {
            float u  = uim[s * 32 + colx];
            float y0 = dir_step<false>(P0, u, up, xh0a, xh1a, xv0a, xv1a, cx0a, cx1a);
            float y2 = dir_step<true >(P2, u, up, xh0b, xh1b, xv0b, xv1b, cx0b, cx1b);
            aim[s * 32 + colx] = __float2half(fmaf(u, om, y0 + y2));
            up = u;
        }
    }
    // ==== pass B: rows descending, d1 (fwd) + d3 (rev) + SiLU finalize ====
    {
        DirP P1, P3;
        dir_init<false>(P1, 64 + hb,  j, A1p, A2p, A3p, A4p, B1p, B2p, C1p, C2p);
        dir_init<true >(P3, 192 + hb, j, A1p, A2p, A3p, A4p, B1p, B2p, C1p, C2p);
        float xh0a=0,xh1a=0,xv0a=0,xv1a=0,cx0a=0,cx1a=0;
        float xh0b=0,xh1b=0,xv0b=0,xv1b=0,cx0b=0,cx1b=0;
        float up = 0.f;
        #pragma unroll 4
        for (int s = 0; s < 32; ++s) {
            int   r  = 31 - s;
            float u  = uim[r * 32 + colx];
            float y1 = dir_step<false>(P1, u, up, xh0a, xh1a, xv0a, xv1a, cx0a, cx1a);
            float y3 = dir_step<true >(P3, u, up, xh0b, xh1b, xv0b, xv1b, cx0b, cx1b);
            float z  = __half2float(aim[r * 32 + colx]) + y1 + y3;
            float sg = 1.0f / (1.0f + __expf(-z));
            aim[r * 32 + colx] = __float2half(z * sg);   // in-place finalize
            up = u;
        }
    }
    __syncthreads();

    // ---- coalesced store-out (fp16 -> f32) ----
    #pragma unroll 4
    for (int it = 0; it < 32; ++it) {
        int pix = it * 32 + (t >> 3);
        out[(size_t)pix * M_TOT + (m0 + simg)] =
            __half2float(a_lds[simg * 1024 + (pix ^ (simg << 2))]);
    }
}

extern "C" void kernel_launch(void* const* d_in, const int* in_sizes, int n_in,
                              void* d_out, int out_size, void* d_ws, size_t ws_size,
                              hipStream_t stream) {
    const float* x  = (const float*)d_in[0];
    const float* A1 = (const float*)d_in[1];
    const float* A2 = (const float*)d_in[2];
    const float* A3 = (const float*)d_in[3];
    const float* A4 = (const float*)d_in[4];
    const float* B1 = (const float*)d_in[5];
    const float* B2 = (const float*)d_in[6];
    const float* C1 = (const float*)d_in[7];
    const float* C2 = (const float*)d_in[8];
    const float* om = (const float*)d_in[9];
    float* out = (float*)d_out;
    hipLaunchKernelGGL(ssm2d_kernel, dim3(M_TOT / NPB), dim3(THREADS), 0, stream,
                       x, A1, A2, A3, A4, B1, B2, C1, C2, om, out);
}